// Round 11
// baseline (363.080 us; speedup 1.0000x reference)
//
#include <hip/hip_runtime.h>

#define N_NODES 50000
#define N_EDGES 600000
#define N_RELS  19
#define D_IN    128
#define D_HID   64
#define D_OUT   2
#define BSH     9                                   // src bucket = 512 nodes
#define NB      ((N_NODES + 511) >> 9)              // 98
#define NSEG    (NB * N_RELS)                       // 1862
#define NTILE_CAP (NSEG + (N_EDGES + 127) / 128)    // 6550 (hard upper bound)
#define SL_BLOCKS ((N_NODES + 63) / 64)             // 782
#define PREP_ELEMS (N_RELS * D_HID * D_IN + 64 * 64 + D_HID * D_IN)  // 167936
#define PREP_BLOCKS ((PREP_ELEMS + 255) / 256)      // 656

typedef unsigned short u16;
typedef unsigned int   u32;
typedef __attribute__((ext_vector_type(8))) short sfrag;   // 8 bf16 (4 VGPRs)
typedef __attribute__((ext_vector_type(4))) float f32x4;   // 4 fp32 acc

__device__ __forceinline__ u16 f2bf(float f){
  union { float f; u32 i; } v; v.f = f;
  u32 r = v.i + 0x7fffu + ((v.i >> 16) & 1u);  // RNE
  return (u16)(r >> 16);
}
__device__ __forceinline__ float bf2f(u16 u){
  union { u32 i; float f; } v; v.i = ((u32)u) << 16; return v.f;
}
__device__ __forceinline__ u32 pack2(float lo, float hi){
  return (u32)f2bf(lo) | ((u32)f2bf(hi) << 16);
}

// feat->featb bf16 (float4), (src-bucket,rel) seg histogram, dst histogram.
__global__ __launch_bounds__(256) void k_pre(const float* __restrict__ feat,
                                             u16* __restrict__ featb,
                                             const int* __restrict__ src,
                                             const int* __restrict__ et,
                                             const int* __restrict__ dst,
                                             int* __restrict__ seg_hist,
                                             int* __restrict__ hist_dst){
  int i = blockIdx.x * 256 + threadIdx.x;          // 1.6M float4 elems
  float4 f = ((const float4*)feat)[i];
  uint2 p; p.x = pack2(f.x, f.y); p.y = pack2(f.z, f.w);
  ((uint2*)featb)[i] = p;
  if (i < N_EDGES) {
    int key = (src[i] >> BSH) * N_RELS + et[i];
    atomicAdd(&seg_hist[key * 16], 1);
    atomicAdd(&hist_dst[dst[i]], 1);
  }
}

// Blocks 0..195: dst slot-region allocation. Block 196: segment scan + TILE
// TABLE (tseg/tstart/ntile). Blocks 197..: weight transform:
// W1Tb [19][64][128] (j-major); W2allT [64][64]: row j=2r+o = W2[r][:,o],
// rows 38/39 = loop2 cols, rest 0; loop1Tb [64][128].
__global__ __launch_bounds__(256) void k_prep(
    const int* __restrict__ hist_dst, int* __restrict__ dstart,
    int* __restrict__ cur_dst, int* __restrict__ gcnt,
    const int* __restrict__ seg_hist, int* __restrict__ seg_off,
    int* __restrict__ cur_seg, int* __restrict__ ntile,
    int* __restrict__ tseg, int* __restrict__ tstart,
    const float* __restrict__ W1, const float* __restrict__ loop1,
    const float* __restrict__ W2, const float* __restrict__ loop2,
    u16* __restrict__ W1Tb, u16* __restrict__ loop1Tb,
    u16* __restrict__ W2allT){
  if (blockIdx.x >= 197) {                      // ---- weight transform ----
    int idx = (blockIdx.x - 197) * 256 + threadIdx.x;
    const int T1  = N_RELS * D_HID * D_IN;      // 155648
    const int T2c = T1 + 64 * 64;               // 159744
    const int T3  = T2c + D_HID * D_IN;         // 167936
    if (idx < T1) {
      int r = idx / (D_HID * D_IN);
      int t = idx - r * (D_HID * D_IN);
      int j = t >> 7, d = t & 127;
      W1Tb[idx] = f2bf(W1[(r * D_IN + d) * D_HID + j]);
    } else if (idx < T2c) {
      int k2 = idx - T1;
      int j = k2 >> 6, k = k2 & 63;
      float val = 0.f;
      if (j < N_RELS * D_OUT)      val = W2[((j >> 1) * D_HID + k) * D_OUT + (j & 1)];
      else if (j == 38)            val = loop2[k * 2];
      else if (j == 39)            val = loop2[k * 2 + 1];
      W2allT[k2] = f2bf(val);
    } else if (idx < T3) {
      int k2 = idx - T2c;
      int j = k2 >> 7, d = k2 & 127;
      loop1Tb[k2] = f2bf(loop1[d * D_HID + j]);
    }
    return;
  }
  if (blockIdx.x == 196) {                      // ---- seg scan + tile table ----
    __shared__ int se_s[256], st_s[256];
    int tid = threadIdx.x;
    const int PER = (NSEG + 255) / 256;         // 8
    int lo = tid * PER, hi = lo + PER; if (hi > NSEG) hi = NSEG; if (lo > NSEG) lo = NSEG;
    int se = 0, st = 0;
    for (int i = lo; i < hi; ++i) { int c = seg_hist[i * 16]; se += c; st += (c + 127) >> 7; }
    se_s[tid] = se; st_s[tid] = st;
    __syncthreads();
    if (tid == 0) {
      int a = 0, b = 0;
      for (int j = 0; j < 256; ++j) { int x = se_s[j], y = st_s[j]; se_s[j] = a; st_s[j] = b; a += x; b += y; }
      ntile[0] = b;
    }
    __syncthreads();
    int eo = se_s[tid], to = st_s[tid];
    for (int i = lo; i < hi; ++i) {
      int c = seg_hist[i * 16];
      seg_off[i] = eo; cur_seg[i * 16] = eo;
      int nt = (c + 127) >> 7;
      for (int k = 0; k < nt; ++k) { tseg[to + k] = i; tstart[to + k] = eo + (k << 7); }
      eo += c; to += nt;
    }
    if (hi == NSEG) seg_off[NSEG] = eo;         // == N_EDGES
    return;
  }
  // ---- dst slot-region allocation ----
  __shared__ int wbase[4];
  int tid = threadIdx.x, lane = tid & 63, wv = tid >> 6;
  int n = blockIdx.x * 256 + tid;
  int v = (n < N_NODES) ? hist_dst[n] : 0;
  int x = v;
  #pragma unroll
  for (int o = 1; o < 64; o <<= 1) { int u = __shfl_up(x, o); if (lane >= o) x += u; }
  if (lane == 63) wbase[wv] = atomicAdd(gcnt, x);   // x = wave total
  __syncthreads();
  int start = wbase[wv] + x - v;
  if (n < N_NODES) { dstart[n] = start; cur_dst[n] = start; }
}

// Scatter edges into perm, grouped by (src-bucket, rel). One atomic, 4B write.
__global__ __launch_bounds__(256) void k_scatter(const int* __restrict__ src,
                                                 const int* __restrict__ et,
                                                 int* __restrict__ cur_seg,
                                                 int* __restrict__ perm){
  int e = blockIdx.x * 256 + threadIdx.x;
  if (e >= N_EDGES) return;
  int key = (src[e] >> BSH) * N_RELS + et[e];
  int p = atomicAdd(&cur_seg[key * 16], 1);
  perm[p] = e;
}

// Blocks < NTILE_CAP: one 128-edge rel-pure tile per block (R2's verified
// tile-per-block scheme, best-measured k_se1 form). Per tile: B staged in LDS,
// slot atomic early, sd2 = {(src<<5)|rel, dst} written SEQUENTIALLY at the
// src-slot (replaces srel's scattered 4B write -> no RFO tax), A-gather,
// MFMA, posIds, barrier, coalesced dst-slot msgbuf writeout.
// Blocks >= NTILE_CAP: dense self-loop GEMM -> agg1b (bf16, R8/R10-verified).
__global__ __launch_bounds__(256, 4) void k_se1(
    const u16* __restrict__ featb, const u16* __restrict__ W1Tb,
    const u16* __restrict__ loop1Tb, const float* __restrict__ b1,
    const int* __restrict__ src, const int* __restrict__ dst,
    const int* __restrict__ perm, const int* __restrict__ seg_off,
    const int* __restrict__ ntile_p, const int* __restrict__ tseg,
    const int* __restrict__ tstart, int* __restrict__ cur_dst,
    int2* __restrict__ sd2, u16* __restrict__ msgbuf,
    u16* __restrict__ agg1b){
  __shared__ __align__(16) u16 Bls[64][136];    // 17408 B
  __shared__ __align__(16) u16 msg[128][72];    // 18432 B; wave-private stripes
  __shared__ int posIds[128];
  int tid = threadIdx.x, lane = tid & 63, w4 = tid >> 6;
  int r16 = lane & 15, c4 = lane >> 4;

  if (blockIdx.x >= NTILE_CAP) {                // ---- self-loop path ----
    int base = (blockIdx.x - NTILE_CAP) * 64;
    { int j = tid >> 2, sg = tid & 3;
      const uint4* g = (const uint4*)(loop1Tb + j * 128) + sg * 4;
      uint4* d = (uint4*)&Bls[j][sg * 32];
      d[0] = g[0]; d[1] = g[1]; d[2] = g[2]; d[3] = g[3]; }
    int arow = base + w4 * 16 + r16; if (arow >= N_NODES) arow = N_NODES - 1;
    sfrag aF[4];
    #pragma unroll
    for (int kk = 0; kk < 4; ++kk)
      aF[kk] = *(const sfrag*)(featb + (size_t)arow * D_IN + kk * 32 + c4 * 8);
    __syncthreads();
    #pragma unroll
    for (int ct = 0; ct < 4; ++ct) {
      int col = ct * 16 + r16;
      f32x4 acc = {0.f, 0.f, 0.f, 0.f};
      #pragma unroll
      for (int kk = 0; kk < 4; ++kk) {
        sfrag bF = *(const sfrag*)&Bls[ct * 16 + r16][kk * 32 + c4 * 8];
        acc = __builtin_amdgcn_mfma_f32_16x16x32_bf16(aF[kk], bF, acc, 0, 0, 0);
      }
      float bias = b1[col];
      #pragma unroll
      for (int reg = 0; reg < 4; ++reg) {
        float v = acc[reg] + bias;
        float o = __shfl_xor(v, 1);
        if (!(lane & 1))
          *(u32*)&msg[w4 * 16 + c4 * 4 + reg][col] = pack2(v, o);   // wave stripe
      }
    }
    { int j = lane >> 2, q = lane & 3;          // wave-private 32B/thread flush
      int n = base + w4 * 16 + j;
      if (n < N_NODES) {
        const uint4* mr = (const uint4*)&msg[w4 * 16 + j][q * 16];
        uint4* d = (uint4*)(agg1b + (size_t)n * D_HID + q * 16);
        d[0] = mr[0]; d[1] = mr[1];
      } }
    return;
  }

  // ---- edge-tile path ----
  int nt = *ntile_p;
  int pb = blockIdx.x;
  if (pb >= nt) return;                         // pad blocks (cap > actual)
  int q8 = nt >> 3, r8 = nt & 7;                // bijective XCD chunk map
  int xcd = pb & 7, cidx = pb >> 3;
  int b = (xcd < r8 ? xcd * (q8 + 1) : r8 * (q8 + 1) + (xcd - r8) * q8) + cidx;

  int seg = tseg[b];
  int ts  = tstart[b];
  int vc  = seg_off[seg + 1] - ts; if (vc > 128) vc = 128;
  int rel = seg - (seg / N_RELS) * N_RELS;      // seg % 19

  { // B tile: W1Tb[rel], 64 x 128 bf16 (16 KB, L2-resident)
    int j = tid >> 2, sg = tid & 3;
    const uint4* g = (const uint4*)(W1Tb + ((size_t)rel * 64 + j) * 128) + sg * 4;
    uint4* d = (uint4*)&Bls[j][sg * 32];
    d[0] = g[0]; d[1] = g[1]; d[2] = g[2]; d[3] = g[3];
  }
  // slot atomic EARLY (hidden under B-stage + A-gather) + SEQUENTIAL sd2 write
  int myPos = -1;
  if (tid < 128 && tid < vc) {
    int e = perm[ts + tid];
    int s2 = src[e], d2 = dst[e];
    myPos = atomicAdd(&cur_dst[d2], 1);
    sd2[ts + tid] = make_int2((s2 << 5) | rel, d2);   // streaming 8B, no RFO
  }
  // A fragments direct global->VGPR (featb L2-bucket-local)
  sfrag aF[2][4];
  #pragma unroll
  for (int mt = 0; mt < 2; ++mt) {
    int row = w4 * 32 + mt * 16 + r16;
    int rr = row < vc ? row : vc - 1;
    int s = src[perm[ts + rr]];
    const u16* ap = featb + (size_t)s * D_IN + c4 * 8;
    #pragma unroll
    for (int kk = 0; kk < 4; ++kk)
      aF[mt][kk] = *(const sfrag*)(ap + kk * 32);
  }
  __syncthreads();                              // Bls ready
  #pragma unroll
  for (int ct = 0; ct < 4; ++ct) {
    sfrag bF[4];
    #pragma unroll
    for (int kk = 0; kk < 4; ++kk)
      bF[kk] = *(const sfrag*)&Bls[ct * 16 + r16][kk * 32 + c4 * 8];
    #pragma unroll
    for (int mt = 0; mt < 2; ++mt) {
      f32x4 acc = {0.f, 0.f, 0.f, 0.f};
      #pragma unroll
      for (int kk = 0; kk < 4; ++kk)
        acc = __builtin_amdgcn_mfma_f32_16x16x32_bf16(aF[mt][kk], bF[kk], acc, 0, 0, 0);
      #pragma unroll
      for (int reg = 0; reg < 4; ++reg) {
        float v = acc[reg];
        float o = __shfl_xor(v, 1);
        if (!(lane & 1)) {
          int orow = w4 * 32 + mt * 16 + c4 * 4 + reg;
          *(u32*)&msg[orow][ct * 16 + r16] = pack2(v, o);
        }
      }
    }
  }
  if (tid < 128) posIds[tid] = myPos;
  __syncthreads();
  { int row = tid >> 1, half = tid & 1;         // coalesced 64B/thread writeout
    int pos = posIds[row];
    if (pos >= 0) {
      const uint4* mr = (const uint4*)&msg[row][half * 32];
      uint4* d = (uint4*)(msgbuf + (size_t)pos * D_HID + half * 32);
      d[0] = mr[0]; d[1] = mr[1]; d[2] = mr[2]; d[3] = mr[3];
    } }
}

// Fused: message aggregation (one node per wave, sequential msgbuf read) +
// self-loop + relu -> h1 (LDS f32, wave-private), then T2 row via 40-lane dot:
// T2[n][2r+o] = h1[n]@W2[r][:,o]; cols 38/39 carry loop2 -> out init (+b2).
__global__ __launch_bounds__(256) void k_agg(
    const u16* __restrict__ msgbuf, const int* __restrict__ dstart,
    const int* __restrict__ cnt, const u16* __restrict__ agg1b,
    const u16* __restrict__ W2allT, const float* __restrict__ b2,
    float* __restrict__ T2f, float* __restrict__ out){
  __shared__ u16   W2ls[64][66];                // padded: bank-spread rows
  __shared__ float h1s[4][68];
  int tid = threadIdx.x, wv = tid >> 6, lane = tid & 63;
  for (int i = tid; i < 64 * 64; i += 256) W2ls[i >> 6][i & 63] = W2allT[i];
  int n = blockIdx.x * 4 + wv;
  int s = dstart[n], epos = s + cnt[n];
  int h = lane >> 5, cc = lane & 31;
  float a0 = 0.f, a1 = 0.f;
  for (int i = s + h; i < epos; i += 2) {
    u32 v = ((const u32*)msgbuf)[(size_t)i * 32 + cc];
    a0 += bf2f((u16)(v & 0xffffu));
    a1 += bf2f((u16)(v >> 16));
  }
  a0 += __shfl_down(a0, 32);
  a1 += __shfl_down(a1, 32);
  if (h == 0) {
    u32 sv = ((const u32*)agg1b)[(size_t)n * 32 + cc];
    float v0 = a0 + bf2f((u16)(sv & 0xffffu));
    float v1 = a1 + bf2f((u16)(sv >> 16));
    v0 = v0 > 0.f ? v0 : 0.f;
    v1 = v1 > 0.f ? v1 : 0.f;
    h1s[wv][2 * cc]     = v0;
    h1s[wv][2 * cc + 1] = v1;
  }
  __syncthreads();                              // W2ls visible (h1s wave-private)
  if (lane < 40) {
    float acc = 0.f;
    #pragma unroll 8
    for (int k = 0; k < 64; ++k)
      acc += bf2f(W2ls[lane][k]) * h1s[wv][k];
    if (lane < 38) T2f[(size_t)n * 40 + lane] = acc;
    else           out[n * 2 + (lane - 38)] = acc + b2[lane - 38];
  }
}

// Layer-2 finish, edge-parallel in SRC-SLOT order: sd2 read sequential, T2f
// gather L2-local (src-bucket order + XCD chunk swizzle), 2 f32 atomics into
// the 400KB out (L2-resident). 2344 blocks = 8*293 -> exact bijective swizzle.
__global__ __launch_bounds__(256) void k_fin(
    const float* __restrict__ T2f, const int2* __restrict__ sd2,
    float* __restrict__ out){
  int pb = blockIdx.x;
  int swz = (pb & 7) * 293 + (pb >> 3);         // 2344 = 8*293 exactly
  int i = swz * 256 + threadIdx.x;
  if (i >= N_EDGES) return;
  int2 v = sd2[i];
  const float* p = T2f + (size_t)(v.x >> 5) * 40 + (v.x & 31) * 2;
  atomicAdd(&out[v.y * 2],     p[0]);
  atomicAdd(&out[v.y * 2 + 1], p[1]);
}

extern "C" void kernel_launch(void* const* d_in, const int* in_sizes, int n_in,
                              void* d_out, int out_size, void* d_ws, size_t ws_size,
                              hipStream_t stream){
  const float* feat  = (const float*)d_in[0];
  const float* W1    = (const float*)d_in[1];
  const float* loop1 = (const float*)d_in[2];
  const float* b1    = (const float*)d_in[3];
  const float* W2    = (const float*)d_in[4];
  const float* loop2 = (const float*)d_in[5];
  const float* b2    = (const float*)d_in[6];
  const int* src     = (const int*)d_in[7];
  const int* dst     = (const int*)d_in[8];
  const int* et      = (const int*)d_in[9];
  float* out = (float*)d_out;

  // workspace layout (16B-aligned), ~104.4 MB total.
  char* w = (char*)d_ws;
  u16*   W1Tb     = (u16*)(w);                   //  311296
  u16*   W2allT   = (u16*)(w + 311296);          //    8192 (64x64 bf16)
  u16*   loop1Tb  = (u16*)(w + 319488);          //   16384
  int*   seg_hist = (int*)(w + 335872);          //  119168 (1862 x 64B) ┐
  int*   gcnt     = (int*)(w + 455040);          //      64              ├ memset (319232 B)
  int*   hist_dst = (int*)(w + 455104);          //  200000              ┘
  int*   seg_off  = (int*)(w + 655104);          //    7488
  int*   cur_seg  = (int*)(w + 662592);          //  119168 (64B-padded)
  int*   ntile    = (int*)(w + 781760);          //      64
  int*   tseg     = (int*)(w + 781824);          //   26240
  int*   tstart   = (int*)(w + 808064);          //   26240
  int*   dstart   = (int*)(w + 834304);          //  200000
  int*   cur_dst  = (int*)(w + 1034304);         //  200000
  int*   perm     = (int*)(w + 1234304);         // 2400000
  int2*  sd2      = (int2*)(w + 3634304);        // 4800000
  u16*   featb    = (u16*)(w + 8434304);         // 12.8 MB (T2f aliases; featb dead after k_se1)
  float* T2f      = (float*)(w + 8434304);       //  8.0 MB (50000 x 40 f32)
  u16*   agg1b    = (u16*)(w + 21234304);        //  6.4 MB
  u16*   msgbuf   = (u16*)(w + 27634304);        // 76.8 MB -> 104434304

  hipMemsetAsync(w + 335872, 0, 319232, stream);
  k_pre     <<<6250, 256, 0, stream>>>(feat, featb, src, et, dst, seg_hist, hist_dst);
  k_prep    <<<197 + PREP_BLOCKS, 256, 0, stream>>>(
                hist_dst, dstart, cur_dst, gcnt, seg_hist, seg_off, cur_seg,
                ntile, tseg, tstart, W1, loop1, W2, loop2, W1Tb, loop1Tb, W2allT);
  k_scatter <<<2344, 256, 0, stream>>>(src, et, cur_seg, perm);
  k_se1     <<<NTILE_CAP + SL_BLOCKS, 256, 0, stream>>>(
                featb, W1Tb, loop1Tb, b1, src, dst, perm, seg_off,
                ntile, tseg, tstart, cur_dst, sd2, msgbuf, agg1b);
  k_agg     <<<12500, 256, 0, stream>>>(msgbuf, dstart, hist_dst, agg1b,
                                        W2allT, b2, T2f, out);
  k_fin     <<<2344, 256, 0, stream>>>(T2f, sd2, out);
}